// Round 1
// baseline (59.552 us; speedup 1.0000x reference)
//
#include <hip/hip_runtime.h>

#define F_BINS 257

// One thread per frequency bin. Single block of 320 (5 waves) covers 257 bins.
// All inputs are float32; output is float32: [x_enh (F,1,2) | new_cache (F,2,2)].
__global__ __launch_bounds__(320) void CCM_77043123355820_kernel(
    const float* __restrict__ m,      // (27, F) flat: m[ch*F + f]
    const float* __restrict__ x,      // (F, 2)  flat: x[f*2 + c]
    const float* __restrict__ cache,  // (F, 2, 2) flat: cache[f*4 + t*2 + c]
    float* __restrict__ out)          // [514 floats x_enh | 1028 floats new_cache]
{
    const int f = threadIdx.x;
    if (f >= F_BINS) return;

    // H[k] = V-combined filter, k = time*3 + tap
    float Hr[9], Hi[9];
    #pragma unroll
    for (int k = 0; k < 9; ++k) {
        const float m0 = m[k * F_BINS + f];
        const float m1 = m[(9 + k) * F_BINS + f];
        const float m2 = m[(18 + k) * F_BINS + f];
        Hr[k] = m0 - 0.5f * (m1 + m2);
        Hi[k] = 0.86602540378443864676f * (m1 - m2);
    }

    // xc[time][tap]: time 0,1 from cache; time 2 from x. Tap j reads freq f+j-1
    // with zero padding at the edges.
    float xr[3][3], xi[3][3];
    #pragma unroll
    for (int j = 0; j < 3; ++j) {
        const int fp = f + j - 1;
        const bool ok = (fp >= 0) && (fp < F_BINS);
        xr[0][j] = ok ? cache[fp * 4 + 0] : 0.0f;
        xi[0][j] = ok ? cache[fp * 4 + 1] : 0.0f;
        xr[1][j] = ok ? cache[fp * 4 + 2] : 0.0f;
        xi[1][j] = ok ? cache[fp * 4 + 3] : 0.0f;
        xr[2][j] = ok ? x[fp * 2 + 0] : 0.0f;
        xi[2][j] = ok ? x[fp * 2 + 1] : 0.0f;
    }

    float re = 0.0f, im = 0.0f;
    #pragma unroll
    for (int i = 0; i < 3; ++i) {
        #pragma unroll
        for (int j = 0; j < 3; ++j) {
            const int k = i * 3 + j;
            re += Hr[k] * xr[i][j] - Hi[k] * xi[i][j];
            im += Hr[k] * xi[i][j] + Hi[k] * xr[i][j];
        }
    }

    // x_enh: (1, F, 1, 2) flat -> f*2 + c
    out[f * 2 + 0] = re;
    out[f * 2 + 1] = im;

    // new_cache: (1, F, 2, 2) flat at offset 2*F -> f*4 + t*2 + c
    // new_cache[f][0][:] = cache[f][1][:];  new_cache[f][1][:] = x[f][:]
    float* nc = out + 2 * F_BINS;
    nc[f * 4 + 0] = cache[f * 4 + 2];
    nc[f * 4 + 1] = cache[f * 4 + 3];
    nc[f * 4 + 2] = x[f * 2 + 0];
    nc[f * 4 + 3] = x[f * 2 + 1];
}

extern "C" void kernel_launch(void* const* d_in, const int* in_sizes, int n_in,
                              void* d_out, int out_size, void* d_ws, size_t ws_size,
                              hipStream_t stream) {
    const float* m     = (const float*)d_in[0];
    const float* x     = (const float*)d_in[1];
    const float* cache = (const float*)d_in[2];
    float* out = (float*)d_out;
    CCM_77043123355820_kernel<<<1, 320, 0, stream>>>(m, x, cache, out);
}

// Round 2
// 58.460 us; speedup vs baseline: 1.0187x; 1.0187x over previous
//
#include <hip/hip_runtime.h>

#define F_BINS 257

// One thread per frequency bin; single block of 320 threads (5 waves).
// Inputs float32: m (27,F), x (F,2), cache (F,2,2).
// Output float32 flat: [x_enh (F*2) | new_cache (F*4)].
__global__ __launch_bounds__(320) void CCM_77043123355820_kernel(
    const float* __restrict__ m,
    const float* __restrict__ x,
    const float* __restrict__ cache,
    float* __restrict__ out)
{
    const int f = threadIdx.x;
    if (f >= F_BINS) return;

    // Filter taps: H[k] = m0 - 0.5(m1+m2) + i*(sqrt(3)/2)(m1-m2), k = time*3+tap
    float Hr[9], Hi[9];
    #pragma unroll
    for (int k = 0; k < 9; ++k) {
        const float m0 = m[k * F_BINS + f];
        const float m1 = m[(9 + k) * F_BINS + f];
        const float m2 = m[(18 + k) * F_BINS + f];
        Hr[k] = m0 - 0.5f * (m1 + m2);
        Hi[k] = 0.86602540378443864676f * (m1 - m2);
    }

    // Vectorized neighbor loads: cache bin = one float4 (t0r,t0i,t1r,t1i),
    // x bin = one float2 (r,i). Tap j reads bin f+j-1, zero-padded at edges.
    const float4* __restrict__ c4 = (const float4*)cache;
    const float2* __restrict__ x2 = (const float2*)x;

    float xr[3][3], xi[3][3];
    #pragma unroll
    for (int j = 0; j < 3; ++j) {
        const int fp = f + j - 1;
        if (fp >= 0 && fp < F_BINS) {
            const float4 c = c4[fp];
            const float2 xx = x2[fp];
            xr[0][j] = c.x;  xi[0][j] = c.y;
            xr[1][j] = c.z;  xi[1][j] = c.w;
            xr[2][j] = xx.x; xi[2][j] = xx.y;
        } else {
            xr[0][j] = 0.0f; xi[0][j] = 0.0f;
            xr[1][j] = 0.0f; xi[1][j] = 0.0f;
            xr[2][j] = 0.0f; xi[2][j] = 0.0f;
        }
    }

    float re = 0.0f, im = 0.0f;
    #pragma unroll
    for (int i = 0; i < 3; ++i) {
        #pragma unroll
        for (int j = 0; j < 3; ++j) {
            const int k = i * 3 + j;
            re = fmaf(Hr[k], xr[i][j], re);
            re = fmaf(-Hi[k], xi[i][j], re);
            im = fmaf(Hr[k], xi[i][j], im);
            im = fmaf(Hi[k], xr[i][j], im);
        }
    }

    // x_enh: (F,1,2) -> float2 per bin, base is 16B-aligned? out base aligned,
    // float2 needs 8B — fine.
    ((float2*)out)[f] = make_float2(re, im);

    // new_cache at float offset 514 (byte 2056 — 8B aligned, NOT 16B: use float2).
    // new_cache[f] = (cache[f].t1, x[f]) — values already in registers (j==1 taps).
    float2* __restrict__ nc = (float2*)(out + 2 * F_BINS);
    nc[f * 2 + 0] = make_float2(xr[1][1], xi[1][1]);
    nc[f * 2 + 1] = make_float2(xr[2][1], xi[2][1]);
}

extern "C" void kernel_launch(void* const* d_in, const int* in_sizes, int n_in,
                              void* d_out, int out_size, void* d_ws, size_t ws_size,
                              hipStream_t stream) {
    const float* m     = (const float*)d_in[0];
    const float* x     = (const float*)d_in[1];
    const float* cache = (const float*)d_in[2];
    float* out = (float*)d_out;
    CCM_77043123355820_kernel<<<1, 320, 0, stream>>>(m, x, cache, out);
}